// Round 8
// baseline (444.502 us; speedup 1.0000x reference)
//
#include <hip/hip_runtime.h>
#include <hip/hip_bf16.h>

#define D 128
#define SLOPE 0.2f

typedef float f4 __attribute__((ext_vector_type(4)));
typedef unsigned int v2u __attribute__((ext_vector_type(2)));
typedef unsigned int u32;
typedef unsigned short u16;

// ---------- zero fill ----------

__global__ void zero_kernel(int* __restrict__ p, int n) {
  int i = blockIdx.x * blockDim.x + threadIdx.x;
  if (i < n) p[i] = 0;
}

// ---------- counting sort of edges by dst ----------

__global__ void hist_kernel(const int* __restrict__ dst, int* __restrict__ counts, int E) {
  int i = blockIdx.x * blockDim.x + threadIdx.x;
  if (i < E) atomicAdd(&counts[dst[i]], 1);
}

__global__ __launch_bounds__(1024) void scanA(const int* __restrict__ counts,
                                              int* __restrict__ incl,
                                              int* __restrict__ btot, int n) {
  __shared__ int s[1024];
  int t = threadIdx.x;
  int gid = blockIdx.x * 1024 + t;
  int v = (gid < n) ? counts[gid] : 0;
  s[t] = v;
  __syncthreads();
  for (int d = 1; d < 1024; d <<= 1) {
    int u = (t >= d) ? s[t - d] : 0;
    __syncthreads();
    s[t] += u;
    __syncthreads();
  }
  if (gid < n) incl[gid] = s[t];
  if (t == 1023) btot[blockIdx.x] = s[1023];
}

__global__ void scanB(int* __restrict__ btot, int nb) {
  int l = threadIdx.x & 63;
  int o = (l < nb) ? btot[l] : 0;
  int v = o;
  for (int d = 1; d < 64; d <<= 1) {
    int u = __shfl_up(v, d);
    if (l >= d) v += u;
  }
  if (l < nb) btot[l] = v - o;  // exclusive
}

__global__ __launch_bounds__(1024) void scanC(const int* __restrict__ incl,
                                              const int* __restrict__ counts,
                                              const int* __restrict__ btot,
                                              int* __restrict__ offsets,
                                              int* __restrict__ cursor, int n) {
  int gid = blockIdx.x * 1024 + threadIdx.x;
  if (gid < n) {
    int inc = incl[gid];
    int off = btot[blockIdx.x] + inc - counts[gid];
    offsets[gid] = off;
    cursor[gid] = off;
    if (gid == n - 1) offsets[n] = btot[blockIdx.x] + inc;
  }
}

// pos[e] = sorted position of edge e; sperm[p] = src of the edge at position p.

__global__ void scatter_kernel(const int* __restrict__ dst, const int* __restrict__ src,
                               int* __restrict__ cursor, int* __restrict__ pos,
                               int* __restrict__ sperm, int E) {
  int i = blockIdx.x * blockDim.x + threadIdx.x;
  if (i < E) {
    int p = atomicAdd(&cursor[dst[i]], 1);
    pos[i] = p;
    __builtin_nontemporal_store(src[i], &sperm[p]);
  }
}

// ---------- W transpose ----------

__global__ void transpose_w(const float* __restrict__ Wl, const float* __restrict__ Wr,
                            float* __restrict__ wcatT) {
  int i = blockIdx.x * blockDim.x + threadIdx.x;  // 0..32767
  int k = i >> 8, c = i & 255;
  float v = (c < D) ? Wl[c * D + k] : Wr[(c - D) * D + k];
  wcatT[k * 256 + c] = v;
}

// ---------- f32 GEMM: hl = x@Wl^T + bl ; hr = x@Wr^T + br ----------

__global__ __launch_bounds__(256) void gemm_hlr(const float* __restrict__ x,
    const float* __restrict__ wcatT, const float* __restrict__ bl,
    const float* __restrict__ br, float* __restrict__ hl, float* __restrict__ hr,
    int nrows) {
  __shared__ float xs[64 * 128];
  int t = threadIdx.x;
  int row0 = blockIdx.x << 6;
#pragma unroll
  for (int i = 0; i < 8; ++i) {
    int g = t + (i << 8);
    int r = g >> 5, c4 = (g & 31) << 2;
    int gr = row0 + r;
    float4 v = make_float4(0.f, 0.f, 0.f, 0.f);
    if (gr < nrows) v = *(const float4*)(x + (size_t)gr * D + c4);
    *(float4*)(xs + r * 128 + c4) = v;
  }
  __syncthreads();
  int rg = t >> 5, cg = t & 31;
  int r0 = rg << 3, c0 = cg << 3;
  float acc[8][8];
#pragma unroll
  for (int i = 0; i < 8; ++i)
#pragma unroll
    for (int j = 0; j < 8; ++j) acc[i][j] = 0.f;

  for (int kk = 0; kk < 128; kk += 4) {
    float4 xv[8];
#pragma unroll
    for (int i = 0; i < 8; ++i) xv[i] = *(const float4*)(xs + (r0 + i) * 128 + kk);
#pragma unroll
    for (int dk = 0; dk < 4; ++dk) {
      float4 wa = *(const float4*)(wcatT + (kk + dk) * 256 + c0);
      float4 wb = *(const float4*)(wcatT + (kk + dk) * 256 + c0 + 4);
      float wv0 = wa.x, wv1 = wa.y, wv2 = wa.z, wv3 = wa.w;
      float wv4 = wb.x, wv5 = wb.y, wv6 = wb.z, wv7 = wb.w;
#pragma unroll
      for (int i = 0; i < 8; ++i) {
        float xk = (dk == 0) ? xv[i].x : (dk == 1) ? xv[i].y : (dk == 2) ? xv[i].z : xv[i].w;
        acc[i][0] = fmaf(xk, wv0, acc[i][0]);
        acc[i][1] = fmaf(xk, wv1, acc[i][1]);
        acc[i][2] = fmaf(xk, wv2, acc[i][2]);
        acc[i][3] = fmaf(xk, wv3, acc[i][3]);
        acc[i][4] = fmaf(xk, wv4, acc[i][4]);
        acc[i][5] = fmaf(xk, wv5, acc[i][5]);
        acc[i][6] = fmaf(xk, wv6, acc[i][6]);
        acc[i][7] = fmaf(xk, wv7, acc[i][7]);
      }
    }
  }
  float bias[8];
#pragma unroll
  for (int j = 0; j < 8; ++j) bias[j] = (c0 < D) ? bl[c0 + j] : br[c0 - D + j];
#pragma unroll
  for (int i = 0; i < 8; ++i) {
    int gr = row0 + r0 + i;
    if (gr >= nrows) continue;
    float* base = (c0 < D) ? (hl + (size_t)gr * D + c0) : (hr + (size_t)gr * D + (c0 - D));
    float4 o0 = make_float4(acc[i][0] + bias[0], acc[i][1] + bias[1],
                            acc[i][2] + bias[2], acc[i][3] + bias[3]);
    float4 o1 = make_float4(acc[i][4] + bias[4], acc[i][5] + bias[5],
                            acc[i][6] + bias[6], acc[i][7] + bias[7]);
    *(float4*)(base) = o0;
    *(float4*)(base + 4) = o1;
  }
}

// ---------- edge-parallel score: stream alpha in natural order, write bf16 w to sorted slot ----------
// wave = 2 edges: lanes 0-31 edge e0, lanes 32-63 edge e0+1; float4/lane of channels.

__device__ __forceinline__ f4 ld4(const float* p) { return *(const f4*)p; }
__device__ __forceinline__ f4 ld4nt(const float* p) {
  return __builtin_nontemporal_load((const f4*)p);
}
__device__ __forceinline__ u16 bf16r(float f) {
  u32 u = __float_as_uint(f);
  return (u16)((u + 0x7FFFu + ((u >> 16) & 1u)) >> 16);
}

__global__ __launch_bounds__(256) void edge_score(const float* __restrict__ alpha,
    const float* __restrict__ hl, const float* __restrict__ hr,
    const int* __restrict__ src, const int* __restrict__ dst,
    const int* __restrict__ pos, u16* __restrict__ wsrt, int E) {
  int wv = blockIdx.x * 4 + (threadIdx.x >> 6);
  int lane = threadIdx.x & 63;
  int half = lane >> 5;
  int ch = (lane & 31) << 2;
  int e0 = wv << 1;
  if (e0 >= E) return;
  int e1 = (e0 + 1 < E) ? e0 + 1 : e0;
  // wave-uniform scalar loads
  int s0 = src[e0], s1 = src[e1];
  int d0 = dst[e0], d1 = dst[e1];
  int p0 = pos[e0], p1 = pos[e1];
  int s = half ? s1 : s0;
  int dd = half ? d1 : d0;
  int p = half ? p1 : p0;
  int e = e0 + half;

  f4 a = ld4nt(alpha + (size_t)e * D + ch);
  f4 h = ld4(hl + (size_t)s * D + ch);
  f4 g = ld4(hr + (size_t)dd * D + ch);
  f4 t = (h + g) * a;
  u16 b[4];
#pragma unroll
  for (int k = 0; k < 4; ++k) {
    float tt = t[k];
    tt = (tt >= 0.f) ? tt : SLOPE * tt;
    b[k] = bf16r(__expf(tt));
  }
  v2u o;
  o.x = (u32)b[0] | ((u32)b[1] << 16);
  o.y = (u32)b[2] | ((u32)b[3] << 16);
  if (e < E) {
    v2u* rp = (v2u*)((u32*)(wsrt + (size_t)p * D) + (ch >> 1));
    __builtin_nontemporal_store(o, rp);
  }
}

// ---------- per-node aggregation: stream w_sorted, gather x[src] ----------

__global__ __launch_bounds__(256) void node_attn(const float* __restrict__ x,
    const u16* __restrict__ wsrt, const int* __restrict__ sperm,
    const int* __restrict__ offsets, float* __restrict__ out, int n) {
  int wid = threadIdx.x >> 6, lane = threadIdx.x & 63;
  int v = (blockIdx.x << 2) + wid;
  if (v >= n) return;
  int b = offsets[v], e = offsets[v + 1];
  int half = lane >> 5;
  int ch = (lane & 31) << 2;

  if (e == b) {
    if (half == 0) {
      f4 z = {0.f, 0.f, 0.f, 0.f};
      *(f4*)(out + (size_t)v * D + ch) = z;
    }
    return;
  }

  f4 dx = {0.f, 0.f, 0.f, 0.f};
  f4 ox = {0.f, 0.f, 0.f, 0.f};

  int jj[4], ss[4];
  float mk[4];
#define LOADIDX(base, JJ, SSA, MKA)                     \
  {                                                     \
    _Pragma("unroll")                                   \
    for (int u = 0; u < 4; ++u) {                       \
      int idx = (base) + 2 * u + half;                  \
      int j = (idx < e) ? idx : (e - 1);                \
      JJ[u] = j;                                        \
      SSA[u] = sperm[j];                                \
      MKA[u] = (idx < e) ? 1.f : 0.f;                   \
    }                                                   \
  }

  int i = b;
  LOADIDX(i, jj, ss, mk)
  while (true) {
    v2u wb[4];
    f4 xv[4];
#pragma unroll
    for (int u = 0; u < 4; ++u)
      wb[u] = __builtin_nontemporal_load(
          (const v2u*)((const u32*)(wsrt + (size_t)jj[u] * D) + (ch >> 1)));
#pragma unroll
    for (int u = 0; u < 4; ++u) xv[u] = ld4(x + (size_t)ss[u] * D + ch);

    int inext = i + 8;
    bool more = inext < e;
    int jjn[4], ssn[4];
    float mkn[4];
    if (more) LOADIDX(inext, jjn, ssn, mkn)

#pragma unroll
    for (int u = 0; u < 4; ++u) {
      f4 w;
      w[0] = __uint_as_float((wb[u].x & 0xFFFFu) << 16);
      w[1] = __uint_as_float(wb[u].x & 0xFFFF0000u);
      w[2] = __uint_as_float((wb[u].y & 0xFFFFu) << 16);
      w[3] = __uint_as_float(wb[u].y & 0xFFFF0000u);
      w *= mk[u];
      dx += w;
      ox += xv[u] * w;
    }
    if (!more) break;
    i = inext;
#pragma unroll
    for (int u = 0; u < 4; ++u) { jj[u] = jjn[u]; ss[u] = ssn[u]; mk[u] = mkn[u]; }
  }
#undef LOADIDX

#pragma unroll
  for (int k = 0; k < 4; ++k) {
    dx[k] += __shfl_xor(dx[k], 32);
    ox[k] += __shfl_xor(ox[k], 32);
  }
  if (half == 0) {
    f4 r;
#pragma unroll
    for (int k = 0; k < 4; ++k) r[k] = ox[k] / dx[k];
    *(f4*)(out + (size_t)v * D + ch) = r;
  }
}

extern "C" void kernel_launch(void* const* d_in, const int* in_sizes, int n_in,
                              void* d_out, int out_size, void* d_ws, size_t ws_size,
                              hipStream_t stream) {
  const float* x = (const float*)d_in[0];
  const float* alpha = (const float*)d_in[1];
  const float* Wl = (const float*)d_in[2];
  const float* bl = (const float*)d_in[3];
  const float* Wr = (const float*)d_in[4];
  const float* br = (const float*)d_in[5];
  const int* src = (const int*)d_in[6];
  const int* dst = (const int*)d_in[7];
  int N = in_sizes[0] / D;
  int E = in_sizes[6];
  float* out = (float*)d_out;

  char* ws = (char*)d_ws;
  auto al = [](size_t v) { return (v + 255) & ~(size_t)255; };
  size_t off = 0;
  float* hl = (float*)(ws + off); off += al((size_t)N * D * 4);
  float* hr = (float*)(ws + off); off += al((size_t)N * D * 4);
  float* wcatT = (float*)(ws + off); off += al(128 * 256 * 4);
  int* counts = (int*)(ws + off); off += al((size_t)N * 4);
  int* offsets = (int*)(ws + off); off += al((size_t)(N + 1) * 4);
  int* cursor = (int*)(ws + off); off += al((size_t)N * 4);
  int* incl = (int*)(ws + off); off += al((size_t)N * 4);
  int* btot = (int*)(ws + off); off += al(64 * 4);
  int* pos = (int*)(ws + off); off += al((size_t)E * 4);
  int* sperm = (int*)(ws + off); off += al((size_t)E * 4);
  u16* wsrt = (u16*)(ws + off); off += al((size_t)E * D * 2);
  (void)off; (void)ws_size; (void)n_in; (void)out_size;

  const int tb = 256;
  int nb = (N + 1023) / 1024;
  zero_kernel<<<(N + tb - 1) / tb, tb, 0, stream>>>(counts, N);
  hist_kernel<<<(E + tb - 1) / tb, tb, 0, stream>>>(dst, counts, E);
  scanA<<<nb, 1024, 0, stream>>>(counts, incl, btot, N);
  scanB<<<1, 64, 0, stream>>>(btot, nb);
  scanC<<<nb, 1024, 0, stream>>>(incl, counts, btot, offsets, cursor, N);
  scatter_kernel<<<(E + tb - 1) / tb, tb, 0, stream>>>(dst, src, cursor, pos, sperm, E);
  transpose_w<<<(128 * 256) / tb, tb, 0, stream>>>(Wl, Wr, wcatT);
  gemm_hlr<<<(N + 63) / 64, 256, 0, stream>>>(x, wcatT, bl, br, hl, hr, N);
  edge_score<<<(E / 2 + 3) / 4, 256, 0, stream>>>(alpha, hl, hr, src, dst, pos, wsrt, E);
  node_attn<<<(N + 3) / 4, 256, 0, stream>>>(x, wsrt, sperm, offsets, out, N);
}

// Round 9
// 287.130 us; speedup vs baseline: 1.5481x; 1.5481x over previous
//
#include <hip/hip_runtime.h>
#include <hip/hip_bf16.h>

#define D 128
#define SLOPE 0.2f

typedef float f4 __attribute__((ext_vector_type(4)));
typedef unsigned int v4u __attribute__((ext_vector_type(4)));
typedef unsigned short v4h __attribute__((ext_vector_type(4)));
typedef unsigned int u32;
typedef unsigned short u16;

// ---------- zero fill ----------

__global__ void zero_kernel(int* __restrict__ p, int n) {
  int i = blockIdx.x * blockDim.x + threadIdx.x;
  if (i < n) p[i] = 0;
}

// ---------- counting sort of edges by dst ----------

__global__ void hist_kernel(const int* __restrict__ dst, int* __restrict__ counts, int E) {
  int i = blockIdx.x * blockDim.x + threadIdx.x;
  if (i < E) atomicAdd(&counts[dst[i]], 1);
}

__global__ __launch_bounds__(1024) void scanA(const int* __restrict__ counts,
                                              int* __restrict__ incl,
                                              int* __restrict__ btot, int n) {
  __shared__ int s[1024];
  int t = threadIdx.x;
  int gid = blockIdx.x * 1024 + t;
  int v = (gid < n) ? counts[gid] : 0;
  s[t] = v;
  __syncthreads();
  for (int d = 1; d < 1024; d <<= 1) {
    int u = (t >= d) ? s[t - d] : 0;
    __syncthreads();
    s[t] += u;
    __syncthreads();
  }
  if (gid < n) incl[gid] = s[t];
  if (t == 1023) btot[blockIdx.x] = s[1023];
}

__global__ void scanB(int* __restrict__ btot, int nb) {
  int l = threadIdx.x & 63;
  int o = (l < nb) ? btot[l] : 0;
  int v = o;
  for (int d = 1; d < 64; d <<= 1) {
    int u = __shfl_up(v, d);
    if (l >= d) v += u;
  }
  if (l < nb) btot[l] = v - o;  // exclusive
}

__global__ __launch_bounds__(1024) void scanC(const int* __restrict__ incl,
                                              const int* __restrict__ counts,
                                              const int* __restrict__ btot,
                                              int* __restrict__ offsets,
                                              int* __restrict__ cursor, int n) {
  int gid = blockIdx.x * 1024 + threadIdx.x;
  if (gid < n) {
    int inc = incl[gid];
    int off = btot[blockIdx.x] + inc - counts[gid];
    offsets[gid] = off;
    cursor[gid] = off;
    if (gid == n - 1) offsets[n] = btot[blockIdx.x] + inc;
  }
}

__global__ void scatter_kernel(const int* __restrict__ dst, const int* __restrict__ src,
                               int* __restrict__ cursor, long long* __restrict__ eperm, int E) {
  int i = blockIdx.x * blockDim.x + threadIdx.x;
  if (i < E) {
    int p = atomicAdd(&cursor[dst[i]], 1);
    long long v = (long long)(unsigned int)i | ((long long)src[i] << 32);
    __builtin_nontemporal_store(v, &eperm[p]);
  }
}

// ---------- W transpose ----------

__global__ void transpose_w(const float* __restrict__ Wl, const float* __restrict__ Wr,
                            float* __restrict__ wcatT) {
  int i = blockIdx.x * blockDim.x + threadIdx.x;  // 0..32767
  int k = i >> 8, c = i & 255;
  float v = (c < D) ? Wl[c * D + k] : Wr[(c - D) * D + k];
  wcatT[k * 256 + c] = v;
}

// ---------- f32 GEMM ----------
// hx row (u16[256]): chunk c (16B) = {hl[4c..4c+3] bf16, x[4c..4c+3] bf16}.
// hr stays f32 (read once per node, sequential).

__device__ __forceinline__ u16 bf16r(float f) {
  u32 u = __float_as_uint(f);
  return (u16)((u + 0x7FFFu + ((u >> 16) & 1u)) >> 16);
}

__global__ __launch_bounds__(256) void gemm_hlr(const float* __restrict__ x,
    const float* __restrict__ wcatT, const float* __restrict__ bl,
    const float* __restrict__ br, u16* __restrict__ hx, float* __restrict__ hr,
    int nrows) {
  __shared__ float xs[64 * 128];
  int t = threadIdx.x;
  int row0 = blockIdx.x << 6;
#pragma unroll
  for (int i = 0; i < 8; ++i) {
    int g = t + (i << 8);
    int r = g >> 5, c4 = (g & 31) << 2;
    int gr = row0 + r;
    float4 v = make_float4(0.f, 0.f, 0.f, 0.f);
    if (gr < nrows) v = *(const float4*)(x + (size_t)gr * D + c4);
    *(float4*)(xs + r * 128 + c4) = v;
  }
  __syncthreads();
  int rg = t >> 5, cg = t & 31;
  int r0 = rg << 3, c0 = cg << 3;
  float acc[8][8];
#pragma unroll
  for (int i = 0; i < 8; ++i)
#pragma unroll
    for (int j = 0; j < 8; ++j) acc[i][j] = 0.f;

  for (int kk = 0; kk < 128; kk += 4) {
    float4 xv[8];
#pragma unroll
    for (int i = 0; i < 8; ++i) xv[i] = *(const float4*)(xs + (r0 + i) * 128 + kk);
#pragma unroll
    for (int dk = 0; dk < 4; ++dk) {
      float4 wa = *(const float4*)(wcatT + (kk + dk) * 256 + c0);
      float4 wb = *(const float4*)(wcatT + (kk + dk) * 256 + c0 + 4);
      float wv0 = wa.x, wv1 = wa.y, wv2 = wa.z, wv3 = wa.w;
      float wv4 = wb.x, wv5 = wb.y, wv6 = wb.z, wv7 = wb.w;
#pragma unroll
      for (int i = 0; i < 8; ++i) {
        float xk = (dk == 0) ? xv[i].x : (dk == 1) ? xv[i].y : (dk == 2) ? xv[i].z : xv[i].w;
        acc[i][0] = fmaf(xk, wv0, acc[i][0]);
        acc[i][1] = fmaf(xk, wv1, acc[i][1]);
        acc[i][2] = fmaf(xk, wv2, acc[i][2]);
        acc[i][3] = fmaf(xk, wv3, acc[i][3]);
        acc[i][4] = fmaf(xk, wv4, acc[i][4]);
        acc[i][5] = fmaf(xk, wv5, acc[i][5]);
        acc[i][6] = fmaf(xk, wv6, acc[i][6]);
        acc[i][7] = fmaf(xk, wv7, acc[i][7]);
      }
    }
  }
  float bias[8];
#pragma unroll
  for (int j = 0; j < 8; ++j) bias[j] = (c0 < D) ? bl[c0 + j] : br[c0 - D + j];
#pragma unroll
  for (int i = 0; i < 8; ++i) {
    int gr = row0 + r0 + i;
    if (gr >= nrows) continue;
    if (c0 < D) {
      // hl -> bf16 chunks in hx
      v4h a, b2;
#pragma unroll
      for (int j = 0; j < 4; ++j) a[j] = bf16r(acc[i][j] + bias[j]);
#pragma unroll
      for (int j = 0; j < 4; ++j) b2[j] = bf16r(acc[i][4 + j] + bias[4 + j]);
      u16* rowp = hx + (size_t)gr * 256;
      *(v4h*)(rowp + 2 * c0) = a;
      *(v4h*)(rowp + 2 * c0 + 8) = b2;
    } else {
      float* base = hr + (size_t)gr * D + (c0 - D);
      float4 o0 = make_float4(acc[i][0] + bias[0], acc[i][1] + bias[1],
                              acc[i][2] + bias[2], acc[i][3] + bias[3]);
      float4 o1 = make_float4(acc[i][4] + bias[4], acc[i][5] + bias[5],
                              acc[i][6] + bias[6], acc[i][7] + bias[7]);
      *(float4*)(base) = o0;
      *(float4*)(base + 4) = o1;
    }
  }
  // x tile (in LDS) -> bf16 into hx chunk slots [4..7]
#pragma unroll
  for (int i = 0; i < 8; ++i) {
    int g = t + (i << 8);
    int r = g >> 5, c4 = (g & 31) << 2;
    int gr = row0 + r;
    if (gr < nrows) {
      const float* sp = xs + r * 128 + c4;
      v4h h;
#pragma unroll
      for (int j = 0; j < 4; ++j) h[j] = bf16r(sp[j]);
      *(v4h*)(hx + (size_t)gr * 256 + 2 * c4 + 4) = h;
    }
  }
}

// ---------- per-node fused softmax + aggregation ----------
// 1 wave per node; lanes 0-31 edge i, lanes 32-63 edge i+1.
// Per edge: ONE 16B/lane gather of hx (hl+x bf16) + one 16B/lane alpha gather.

__device__ __forceinline__ f4 ld4(const float* p) { return *(const f4*)p; }
__device__ __forceinline__ f4 ld4nt(const float* p) {
  return __builtin_nontemporal_load((const f4*)p);
}

__global__ __launch_bounds__(256) void node_attn(const u16* __restrict__ hx,
    const float* __restrict__ alpha, const float* __restrict__ hr,
    const long long* __restrict__ eperm, const int* __restrict__ offsets,
    float* __restrict__ out, int n) {
  int wid = threadIdx.x >> 6, lane = threadIdx.x & 63;
  int v = (blockIdx.x << 2) + wid;
  if (v >= n) return;
  int b = offsets[v], e = offsets[v + 1];
  int half = lane >> 5;
  int ch = (lane & 31) << 2;

  if (e == b) {
    if (half == 0) {
      f4 z = {0.f, 0.f, 0.f, 0.f};
      *(f4*)(out + (size_t)v * D + ch) = z;
    }
    return;
  }

  f4 hrv = ld4(hr + (size_t)v * D + ch);
  f4 dx = {0.f, 0.f, 0.f, 0.f};
  f4 ox = {0.f, 0.f, 0.f, 0.f};

  int ed[4], ss[4];
  float mk[4];
#define LOADIDX(base, EDA, SSA, MKA)                    \
  {                                                     \
    _Pragma("unroll")                                   \
    for (int u = 0; u < 4; ++u) {                       \
      int idx = (base) + 2 * u + half;                  \
      int j = (idx < e) ? idx : (e - 1);                \
      long long pq = eperm[j];                          \
      EDA[u] = (int)(unsigned int)pq;                   \
      SSA[u] = (int)(pq >> 32);                         \
      MKA[u] = (idx < e) ? 1.f : 0.f;                   \
    }                                                   \
  }

  int i = b;
  LOADIDX(i, ed, ss, mk)
  while (true) {
    f4 av[4];
    v4u gv[4];
#pragma unroll
    for (int u = 0; u < 4; ++u) av[u] = ld4nt(alpha + (size_t)ed[u] * D + ch);
#pragma unroll
    for (int u = 0; u < 4; ++u)
      gv[u] = *(const v4u*)(hx + (size_t)ss[u] * 256 + (ch << 1));

    int inext = i + 8;
    bool more = inext < e;
    int edn[4], ssn[4];
    float mkn[4];
    if (more) LOADIDX(inext, edn, ssn, mkn)

#pragma unroll
    for (int u = 0; u < 4; ++u) {
      f4 h, xv;
      h[0] = __uint_as_float((gv[u].x & 0xFFFFu) << 16);
      h[1] = __uint_as_float(gv[u].x & 0xFFFF0000u);
      h[2] = __uint_as_float((gv[u].y & 0xFFFFu) << 16);
      h[3] = __uint_as_float(gv[u].y & 0xFFFF0000u);
      xv[0] = __uint_as_float((gv[u].z & 0xFFFFu) << 16);
      xv[1] = __uint_as_float(gv[u].z & 0xFFFF0000u);
      xv[2] = __uint_as_float((gv[u].w & 0xFFFFu) << 16);
      xv[3] = __uint_as_float(gv[u].w & 0xFFFF0000u);
      f4 t = (h + hrv) * av[u];
      f4 ev;
#pragma unroll
      for (int k = 0; k < 4; ++k) {
        float tt = t[k];
        tt = (tt >= 0.f) ? tt : SLOPE * tt;
        ev[k] = __expf(tt);
      }
      ev *= mk[u];
      dx += ev;
      ox += xv * ev;
    }
    if (!more) break;
    i = inext;
#pragma unroll
    for (int u = 0; u < 4; ++u) { ed[u] = edn[u]; ss[u] = ssn[u]; mk[u] = mkn[u]; }
  }
#undef LOADIDX

#pragma unroll
  for (int k = 0; k < 4; ++k) {
    dx[k] += __shfl_xor(dx[k], 32);
    ox[k] += __shfl_xor(ox[k], 32);
  }
  if (half == 0) {
    f4 r;
#pragma unroll
    for (int k = 0; k < 4; ++k) r[k] = ox[k] / dx[k];
    *(f4*)(out + (size_t)v * D + ch) = r;
  }
}

extern "C" void kernel_launch(void* const* d_in, const int* in_sizes, int n_in,
                              void* d_out, int out_size, void* d_ws, size_t ws_size,
                              hipStream_t stream) {
  const float* x = (const float*)d_in[0];
  const float* alpha = (const float*)d_in[1];
  const float* Wl = (const float*)d_in[2];
  const float* bl = (const float*)d_in[3];
  const float* Wr = (const float*)d_in[4];
  const float* br = (const float*)d_in[5];
  const int* src = (const int*)d_in[6];
  const int* dst = (const int*)d_in[7];
  int N = in_sizes[0] / D;
  int E = in_sizes[6];
  float* out = (float*)d_out;

  char* ws = (char*)d_ws;
  auto al = [](size_t v) { return (v + 255) & ~(size_t)255; };
  size_t off = 0;
  u16* hx = (u16*)(ws + off); off += al((size_t)N * 256 * 2);
  float* hr = (float*)(ws + off); off += al((size_t)N * D * 4);
  float* wcatT = (float*)(ws + off); off += al(128 * 256 * 4);
  int* counts = (int*)(ws + off); off += al((size_t)N * 4);
  int* offsets = (int*)(ws + off); off += al((size_t)(N + 1) * 4);
  int* cursor = (int*)(ws + off); off += al((size_t)N * 4);
  int* incl = (int*)(ws + off); off += al((size_t)N * 4);
  int* btot = (int*)(ws + off); off += al(64 * 4);
  long long* eperm = (long long*)(ws + off); off += al((size_t)E * 8);
  (void)off; (void)ws_size; (void)n_in; (void)out_size;

  const int tb = 256;
  int nb = (N + 1023) / 1024;
  zero_kernel<<<(N + tb - 1) / tb, tb, 0, stream>>>(counts, N);
  hist_kernel<<<(E + tb - 1) / tb, tb, 0, stream>>>(dst, counts, E);
  scanA<<<nb, 1024, 0, stream>>>(counts, incl, btot, N);
  scanB<<<1, 64, 0, stream>>>(btot, nb);
  scanC<<<nb, 1024, 0, stream>>>(incl, counts, btot, offsets, cursor, N);
  scatter_kernel<<<(E + tb - 1) / tb, tb, 0, stream>>>(dst, src, cursor, eperm, E);
  transpose_w<<<(128 * 256) / tb, tb, 0, stream>>>(Wl, Wr, wcatT);
  gemm_hlr<<<(N + 63) / 64, 256, 0, stream>>>(x, wcatT, bl, br, hx, hr, N);
  node_attn<<<(N + 3) / 4, 256, 0, stream>>>(hx, alpha, hr, eperm, offsets, out, N);
}